// Round 1
// baseline (1216.153 us; speedup 1.0000x reference)
//
#include <hip/hip_runtime.h>
#include <hip/hip_bf16.h>
#include <math.h>

#define LLEN 2048
#define DMODEL 1024
#define NHEAD 16
#define DHEAD 64
#define SCALE 0.125f
#define NEGF -1000000000.0f

typedef __attribute__((ext_vector_type(8))) short short8;
typedef __attribute__((ext_vector_type(4))) float f32x4;

__device__ __forceinline__ unsigned short f2bf(float f) {
  union { float f; unsigned u; } cv; cv.f = f;
  unsigned u = cv.u;
  u += 0x7FFF + ((u >> 16) & 1);
  return (unsigned short)(u >> 16);
}

// ---------------- W transpose + bf16 convert: Wt[n][k] = bf16(W[k][n]) ----------------
__global__ __launch_bounds__(256) void transpose_w(
    const float* __restrict__ Wq, const float* __restrict__ Wk,
    const float* __restrict__ Wv, const float* __restrict__ Wo,
    const float* __restrict__ Wg,
    unsigned short* __restrict__ Wqt, unsigned short* __restrict__ Wkt,
    unsigned short* __restrict__ Wvt, unsigned short* __restrict__ Wot,
    unsigned short* __restrict__ Wgt) {
  const float* W; unsigned short* Wt;
  switch (blockIdx.z) {
    case 0: W = Wq; Wt = Wqt; break;
    case 1: W = Wk; Wt = Wkt; break;
    case 2: W = Wv; Wt = Wvt; break;
    case 3: W = Wo; Wt = Wot; break;
    default: W = Wg; Wt = Wgt; break;
  }
  __shared__ unsigned short tile[64][72];
  int k0 = blockIdx.y * 64, n0 = blockIdx.x * 64;
  int c4 = (threadIdx.x & 15) * 4, r = threadIdx.x >> 4;  // r in 0..15
  for (int rr = r; rr < 64; rr += 16) {
    float4 v = *(const float4*)(W + (size_t)(k0 + rr) * DMODEL + n0 + c4);
    tile[rr][c4 + 0] = f2bf(v.x); tile[rr][c4 + 1] = f2bf(v.y);
    tile[rr][c4 + 2] = f2bf(v.z); tile[rr][c4 + 3] = f2bf(v.w);
  }
  __syncthreads();
  for (int rr = r; rr < 64; rr += 16) {
    ushort4 o;
    o.x = tile[c4 + 0][rr]; o.y = tile[c4 + 1][rr];
    o.z = tile[c4 + 2][rr]; o.w = tile[c4 + 3][rr];
    *(ushort4*)(Wt + (size_t)(n0 + rr) * DMODEL + k0 + c4) = o;
  }
}

// ---------------- LayerNorm -> h_bf16, and x -> x_bf16 ----------------
__global__ __launch_bounds__(256) void ln_kernel(
    const float* __restrict__ x, const float* __restrict__ gamma,
    const float* __restrict__ beta,
    unsigned short* __restrict__ hb, unsigned short* __restrict__ xb) {
  int l = blockIdx.x, t = threadIdx.x;
  float4 v = ((const float4*)(x + (size_t)l * DMODEL))[t];
  float s  = v.x + v.y + v.z + v.w;
  float s2 = v.x * v.x + v.y * v.y + v.z * v.z + v.w * v.w;
  for (int off = 32; off; off >>= 1) {
    s  += __shfl_down(s, off);
    s2 += __shfl_down(s2, off);
  }
  __shared__ float rs[4], rs2[4];
  int wave = t >> 6, lane = t & 63;
  if (lane == 0) { rs[wave] = s; rs2[wave] = s2; }
  __syncthreads();
  float mean = (rs[0] + rs[1] + rs[2] + rs[3]) * (1.0f / DMODEL);
  float var  = (rs2[0] + rs2[1] + rs2[2] + rs2[3]) * (1.0f / DMODEL) - mean * mean;
  float rstd = rsqrtf(var + 1e-5f);
  float4 g = ((const float4*)gamma)[t];
  float4 b = ((const float4*)beta)[t];
  ushort4 hh, xx;
  hh.x = f2bf((v.x - mean) * rstd * g.x + b.x);
  hh.y = f2bf((v.y - mean) * rstd * g.y + b.y);
  hh.z = f2bf((v.z - mean) * rstd * g.z + b.z);
  hh.w = f2bf((v.w - mean) * rstd * g.w + b.w);
  xx.x = f2bf(v.x); xx.y = f2bf(v.y); xx.z = f2bf(v.z); xx.w = f2bf(v.w);
  ((ushort4*)(hb + (size_t)l * DMODEL))[t] = hh;
  ((ushort4*)(xb + (size_t)l * DMODEL))[t] = xx;
}

// ---------------- direct-fragment MFMA GEMM core: 64x64 tile, wave = 16 rows ----------------
__device__ __forceinline__ void mfma_gemm_64x64(
    const unsigned short* __restrict__ A, const unsigned short* __restrict__ Bt,
    int row0, int ncol0, int lm, int quad, f32x4 acc[4]) {
  for (int k0 = 0; k0 < DMODEL; k0 += 64) {
    short8 a0 = *(const short8*)(A + (size_t)(row0 + lm) * DMODEL + k0 + quad * 8);
    short8 a1 = *(const short8*)(A + (size_t)(row0 + lm) * DMODEL + k0 + 32 + quad * 8);
#pragma unroll
    for (int c = 0; c < 4; c++) {
      const unsigned short* bp = Bt + (size_t)(ncol0 + c * 16 + lm) * DMODEL + k0 + quad * 8;
      short8 b0 = *(const short8*)(bp);
      short8 b1 = *(const short8*)(bp + 32);
      acc[c] = __builtin_amdgcn_mfma_f32_16x16x32_bf16(a0, b0, acc[c], 0, 0, 0);
      acc[c] = __builtin_amdgcn_mfma_f32_16x16x32_bf16(a1, b1, acc[c], 0, 0, 0);
    }
  }
}

// ---------------- QKV GEMM + RoPE epilogue ----------------
__global__ __launch_bounds__(256) void gemm_qkv(
    const unsigned short* __restrict__ hb,
    const unsigned short* __restrict__ Wqt, const unsigned short* __restrict__ Wkt,
    const unsigned short* __restrict__ Wvt,
    unsigned short* __restrict__ qb, unsigned short* __restrict__ kb,
    unsigned short* __restrict__ vT) {
  int which = blockIdx.z;
  const unsigned short* Bt = (which == 0) ? Wqt : (which == 1) ? Wkt : Wvt;
  int wave = threadIdx.x >> 6, lane = threadIdx.x & 63;
  int lm = lane & 15, quad = lane >> 4;
  int it = blockIdx.x, head = blockIdx.y;
  int row0 = it * 64 + wave * 16;
  f32x4 acc[4] = {};
  mfma_gemm_64x64(hb, Bt, row0, head * 64, lm, quad, acc);
  __shared__ float tile[64][65];
#pragma unroll
  for (int c = 0; c < 4; c++)
#pragma unroll
    for (int r2 = 0; r2 < 4; r2++)
      tile[wave * 16 + quad * 4 + r2][c * 16 + lm] = acc[c][r2];
  __syncthreads();
  int r = threadIdx.x >> 2, seg = threadIdx.x & 3;
  int lrow = it * 64 + r;
  float vals[16];
#pragma unroll
  for (int i2 = 0; i2 < 16; i2++) vals[i2] = tile[r][seg * 16 + i2];
  if (seg == 0) {  // RoPE on dh 0..15 (applies to q, k AND v per reference)
    float outv[16];
#pragma unroll
    for (int j = 0; j < 8; j++) {
      float invf = powf(10000.f, -(float)j * 0.125f);
      float f = (float)lrow * invf;
      float cs = cosf(f), sn = sinf(f);
      outv[j]     = vals[j] * cs - vals[j + 8] * sn;
      outv[j + 8] = vals[j + 8] * cs + vals[j] * sn;
    }
#pragma unroll
    for (int j = 0; j < 16; j++) vals[j] = outv[j];
  }
  if (which < 2) {
    unsigned short* dst = ((which == 0) ? qb : kb) + ((size_t)head * LLEN + lrow) * DHEAD + seg * 16;
    union { unsigned short u[16]; uint4 v[2]; } tmp;
#pragma unroll
    for (int i2 = 0; i2 < 16; i2++) tmp.u[i2] = f2bf(vals[i2]);
    *(uint4*)dst = tmp.v[0];
    *((uint4*)dst + 1) = tmp.v[1];
  } else {
    __syncthreads();
#pragma unroll
    for (int i2 = 0; i2 < 16; i2++) tile[r][seg * 16 + i2] = vals[i2];
    __syncthreads();
    int dh = threadIdx.x >> 2, ls = threadIdx.x & 3;
    union { unsigned short u[16]; uint4 v[2]; } tmp;
#pragma unroll
    for (int i2 = 0; i2 < 16; i2++) tmp.u[i2] = f2bf(tile[ls * 16 + i2][dh]);
    unsigned short* dst = vT + ((size_t)head * DHEAD + dh) * LLEN + it * 64 + ls * 16;
    *(uint4*)dst = tmp.v[0];
    *((uint4*)dst + 1) = tmp.v[1];
  }
}

// ---------------- fused attention: single pass, no-max softmax, balanced pairing ----
// 128 threads = 2 waves. Each WAVE handles two complementary 16-row groups
// (g and 127-g), so every wave does a constant ~32 tile-iterations regardless
// of dispatch assignment. No __syncthreads: the P-tile LDS bounce is
// wave-private (compiler orders same-wave LDS RAW via lgkmcnt).
__global__ __launch_bounds__(128) void attn_kernel(
    const unsigned short* __restrict__ qb, const unsigned short* __restrict__ kb,
    const unsigned short* __restrict__ vT, const float* __restrict__ prev,
    float* __restrict__ dots, unsigned short* __restrict__ ob,
    float* __restrict__ rinvg) {
  int h = blockIdx.y;
  int wv = threadIdx.x >> 6, lane = threadIdx.x & 63;
  int lm = lane & 15, quad = lane >> 4;
  int g0 = blockIdx.x * 2 + wv;  // 0..63
  const unsigned short* q = qb + (size_t)h * LLEN * DHEAD;
  const unsigned short* k = kb + (size_t)h * LLEN * DHEAD;
  const unsigned short* v = vT + (size_t)h * DHEAD * LLEN;
  const float* pr = prev + (size_t)h * LLEN * LLEN;
  float* drow = dots + (size_t)h * LLEN * LLEN;
  float slope = exp2f(-8.0f * (float)(h + 1) / (float)NHEAD);
  __shared__ __align__(16) unsigned short pt[2][16][72];

  for (int pass = 0; pass < 2; ++pass) {
    int g = pass ? (127 - g0) : g0;   // complementary pairing: constant work/wave
    int row0 = g * 16;
    int jt_end = g >> 2;              // last (diagonal) tile index, inclusive
    short8 qa0 = *(const short8*)(q + (size_t)(row0 + lm) * DHEAD + quad * 8);
    short8 qa1 = *(const short8*)(q + (size_t)(row0 + lm) * DHEAD + 32 + quad * 8);
    f32x4 oacc[4] = {};
    float lsum[4] = {0.f, 0.f, 0.f, 0.f};
    for (int jt = 0; jt <= jt_end; jt++) {
      // ---- QK^T ----
      f32x4 s[4];
#pragma unroll
      for (int c = 0; c < 4; c++) {
        const unsigned short* kp = k + (size_t)(jt * 64 + c * 16 + lm) * DHEAD + quad * 8;
        short8 b0 = *(const short8*)kp;
        short8 b1 = *(const short8*)(kp + 32);
        f32x4 z = {};
        z = __builtin_amdgcn_mfma_f32_16x16x32_bf16(qa0, b0, z, 0, 0, 0);
        z = __builtin_amdgcn_mfma_f32_16x16x32_bf16(qa1, b1, z, 0, 0, 0);
        s[c] = z;
      }
      // ---- dots write + unnormalized exp + lsum + P tile to LDS ----
#pragma unroll
      for (int c = 0; c < 4; c++) {
        int j = jt * 64 + c * 16 + lm;
#pragma unroll
        for (int r = 0; r < 4; r++) {
          int i = row0 + quad * 4 + r;
          int rel = i - j;
          float bias = (rel >= 0) ? (-slope * (float)rel) : NEGF;
          float d = fmaf(s[c][r], SCALE, pr[(size_t)i * LLEN + j]) + bias;
          drow[(size_t)i * LLEN + j] = d;
          float p = __expf(d);   // no-max softmax: d bounded ~±30, safe in f32
          lsum[r] += p;
          pt[wv][quad * 4 + r][c * 16 + lm] = f2bf(p);
        }
      }
      // ---- PV accumulate with unnormalized p ----
      short8 pa0 = *(const short8*)&pt[wv][lm][quad * 8];
      short8 pa1 = *(const short8*)&pt[wv][lm][32 + quad * 8];
#pragma unroll
      for (int c = 0; c < 4; c++) {
        const unsigned short* vp = v + (size_t)(c * 16 + lm) * LLEN + jt * 64 + quad * 8;
        short8 b0 = *(const short8*)vp;
        short8 b1 = *(const short8*)(vp + 32);
        oacc[c] = __builtin_amdgcn_mfma_f32_16x16x32_bf16(pa0, b0, oacc[c], 0, 0, 0);
        oacc[c] = __builtin_amdgcn_mfma_f32_16x16x32_bf16(pa1, b1, oacc[c], 0, 0, 0);
      }
    }
    // ---- row-sum reduce over the 16 lanes sharing a quad ----
    float rv[4];
#pragma unroll
    for (int r = 0; r < 4; r++) {
      float sm = lsum[r];
#pragma unroll
      for (int off = 1; off < 16; off <<= 1) sm += __shfl_xor(sm, off, 16);
      rv[r] = 1.0f / sm;
    }
    // ---- O = (P~ V) * rinv ----
#pragma unroll
    for (int c = 0; c < 4; c++)
#pragma unroll
      for (int r = 0; r < 4; r++)
        ob[(size_t)(row0 + quad * 4 + r) * DMODEL + h * DHEAD + c * 16 + lm] =
            f2bf(oacc[c][r] * rv[r]);
    if (lm == 0) {
#pragma unroll
      for (int r = 0; r < 4; r++)
        rinvg[(size_t)h * LLEN + row0 + quad * 4 + r] = rv[r];
    }
    // ---- masked dots filler (attn zeros handled by attn_norm) ----
    int jstart = (jt_end + 1) * 64;
    int ncols4 = (LLEN - jstart) >> 2;
    if (ncols4 > 0) {
      float4 negv = {NEGF, NEGF, NEGF, NEGF};
      int r = lane >> 2, t4 = lane & 3;
      size_t base = (size_t)(row0 + r) * LLEN + jstart;
      for (int c4 = t4; c4 < ncols4; c4 += 4)
        *(float4*)(drow + base + c4 * 4) = negv;
    }
  }
}

// ---------------- attn_map normalization: attn = exp(dots) * rinv (streamed) ----
__global__ __launch_bounds__(256) void attn_norm(
    const float* __restrict__ dots, const float* __restrict__ rinvg,
    float* __restrict__ attn) {
  int h = blockIdx.y;
  int i0 = blockIdx.x * 8;
  const float* dr = dots + (size_t)h * LLEN * LLEN;
  float* ar = attn + (size_t)h * LLEN * LLEN;
#pragma unroll
  for (int rr = 0; rr < 8; rr++) {
    int i = i0 + rr;
    float rinv = rinvg[(size_t)h * LLEN + i];
    int nwr4 = ((i >> 6) + 1) * 16;  // float4s in the written (non-filler) region
#pragma unroll
    for (int jc = 0; jc < 2; jc++) {
      int j4 = threadIdx.x + jc * 256;
      size_t idx = (size_t)i * LLEN + (size_t)j4 * 4;
      if (j4 < nwr4) {
        float4 d = *(const float4*)(dr + idx);
        float4 o;
        o.x = __expf(d.x) * rinv;  // exp(NEGF) == 0 handles in-tile masked cols
        o.y = __expf(d.y) * rinv;
        o.z = __expf(d.z) * rinv;
        o.w = __expf(d.w) * rinv;
        *(float4*)(ar + idx) = o;
      } else {
        float4 z = {0.f, 0.f, 0.f, 0.f};
        *(float4*)(ar + idx) = z;
      }
    }
  }
}

// ---------------- gate GEMM: sigmoid(x @ Wg + bg) ----------------
__global__ __launch_bounds__(256) void gemm_gate(
    const unsigned short* __restrict__ xb, const unsigned short* __restrict__ Wgt,
    const float* __restrict__ bg, float* __restrict__ gate) {
  int wave = threadIdx.x >> 6, lane = threadIdx.x & 63;
  int lm = lane & 15, quad = lane >> 4;
  int row0 = blockIdx.x * 64 + wave * 16, ncol0 = blockIdx.y * 64;
  f32x4 acc[4] = {};
  mfma_gemm_64x64(xb, Wgt, row0, ncol0, lm, quad, acc);
#pragma unroll
  for (int c = 0; c < 4; c++) {
    int col = ncol0 + c * 16 + lm;
    float bgv = bg[col];
#pragma unroll
    for (int r = 0; r < 4; r++) {
      int i = row0 + quad * 4 + r;
      float g = acc[c][r] + bgv;
      gate[(size_t)i * DMODEL + col] = 1.0f / (1.0f + __expf(-g));
    }
  }
}

// ---------------- output GEMM: y = gate * (o @ Wo + bo) + x ----------------
__global__ __launch_bounds__(256) void gemm_out(
    const unsigned short* __restrict__ ob, const unsigned short* __restrict__ Wot,
    const float* __restrict__ bo, const float* __restrict__ gate,
    const float* __restrict__ x, float* __restrict__ y) {
  int wave = threadIdx.x >> 6, lane = threadIdx.x & 63;
  int lm = lane & 15, quad = lane >> 4;
  int row0 = blockIdx.x * 64 + wave * 16, ncol0 = blockIdx.y * 64;
  f32x4 acc[4] = {};
  mfma_gemm_64x64(ob, Wot, row0, ncol0, lm, quad, acc);
#pragma unroll
  for (int c = 0; c < 4; c++) {
    int col = ncol0 + c * 16 + lm;
    float bov = bo[col];
#pragma unroll
    for (int r = 0; r < 4; r++) {
      int i = row0 + quad * 4 + r;
      size_t idx = (size_t)i * DMODEL + col;
      float y0 = acc[c][r] + bov;
      y[idx] = gate[idx] * y0 + x[idx];
    }
  }
}

extern "C" void kernel_launch(void* const* d_in, const int* in_sizes, int n_in,
                              void* d_out, int out_size, void* d_ws, size_t ws_size,
                              hipStream_t stream) {
  const float* x     = (const float*)d_in[0];
  const float* prev  = (const float*)d_in[1];
  const float* Wq    = (const float*)d_in[2];
  const float* Wk    = (const float*)d_in[3];
  const float* Wv    = (const float*)d_in[4];
  const float* Wo    = (const float*)d_in[5];
  const float* bo    = (const float*)d_in[6];
  const float* gamma = (const float*)d_in[7];
  const float* beta  = (const float*)d_in[8];
  const float* Wg    = (const float*)d_in[9];
  const float* bg    = (const float*)d_in[10];

  float* y    = (float*)d_out;
  float* attn = y + 2097152;          // 2048*1024
  float* dots = attn + 67108864;      // 16*2048*2048

  char* ws = (char*)d_ws;
  unsigned short* hb  = (unsigned short*)(ws + 0);
  unsigned short* xb  = (unsigned short*)(ws + 4194304);
  unsigned short* Wqt = (unsigned short*)(ws + 8388608);
  unsigned short* Wkt = (unsigned short*)(ws + 10485760);
  unsigned short* Wvt = (unsigned short*)(ws + 12582912);
  unsigned short* Wot = (unsigned short*)(ws + 14680064);
  unsigned short* Wgt = (unsigned short*)(ws + 16777216);
  unsigned short* qb  = (unsigned short*)(ws + 18874368);
  unsigned short* kb  = (unsigned short*)(ws + 23068672);
  unsigned short* vT  = (unsigned short*)(ws + 27262976);
  unsigned short* ob  = (unsigned short*)(ws + 31457280);
  float*          gate = (float*)(ws + 35651584);  // ends at 44040192 bytes
  // rinv per (head,row): reuses the hb region, which is dead after gemm_qkv.
  float*          rinvg = (float*)(ws + 0);

  transpose_w<<<dim3(16, 16, 5), 256, 0, stream>>>(Wq, Wk, Wv, Wo, Wg, Wqt, Wkt, Wvt, Wot, Wgt);
  ln_kernel<<<dim3(2048), 256, 0, stream>>>(x, gamma, beta, hb, xb);
  gemm_qkv<<<dim3(32, 16, 3), 256, 0, stream>>>(hb, Wqt, Wkt, Wvt, qb, kb, vT);
  attn_kernel<<<dim3(32, 16), 128, 0, stream>>>(qb, kb, vT, prev, dots, ob, rinvg);
  attn_norm<<<dim3(256, 16), 256, 0, stream>>>(dots, rinvg, attn);
  gemm_gate<<<dim3(32, 16), 256, 0, stream>>>(xb, Wgt, bg, gate);
  gemm_out<<<dim3(32, 16), 256, 0, stream>>>(ob, Wot, bo, gate, x, y);
}

// Round 2
// 1030.387 us; speedup vs baseline: 1.1803x; 1.1803x over previous
//
#include <hip/hip_runtime.h>
#include <hip/hip_bf16.h>
#include <math.h>

#define LLEN 2048
#define DMODEL 1024
#define NHEAD 16
#define DHEAD 64
#define SCALE 0.125f
#define NEGF -1000000000.0f

typedef __attribute__((ext_vector_type(8))) short short8;
typedef __attribute__((ext_vector_type(4))) float f32x4;

__device__ __forceinline__ unsigned short f2bf(float f) {
  union { float f; unsigned u; } cv; cv.f = f;
  unsigned u = cv.u;
  u += 0x7FFF + ((u >> 16) & 1);
  return (unsigned short)(u >> 16);
}

// ---------------- W transpose + bf16 convert: Wt[n][k] = bf16(W[k][n]) ----------------
__global__ __launch_bounds__(256) void transpose_w(
    const float* __restrict__ Wq, const float* __restrict__ Wk,
    const float* __restrict__ Wv, const float* __restrict__ Wo,
    const float* __restrict__ Wg,
    unsigned short* __restrict__ Wqt, unsigned short* __restrict__ Wkt,
    unsigned short* __restrict__ Wvt, unsigned short* __restrict__ Wot,
    unsigned short* __restrict__ Wgt) {
  const float* W; unsigned short* Wt;
  switch (blockIdx.z) {
    case 0: W = Wq; Wt = Wqt; break;
    case 1: W = Wk; Wt = Wkt; break;
    case 2: W = Wv; Wt = Wvt; break;
    case 3: W = Wo; Wt = Wot; break;
    default: W = Wg; Wt = Wgt; break;
  }
  __shared__ unsigned short tile[64][72];
  int k0 = blockIdx.y * 64, n0 = blockIdx.x * 64;
  int c4 = (threadIdx.x & 15) * 4, r = threadIdx.x >> 4;  // r in 0..15
  for (int rr = r; rr < 64; rr += 16) {
    float4 v = *(const float4*)(W + (size_t)(k0 + rr) * DMODEL + n0 + c4);
    tile[rr][c4 + 0] = f2bf(v.x); tile[rr][c4 + 1] = f2bf(v.y);
    tile[rr][c4 + 2] = f2bf(v.z); tile[rr][c4 + 3] = f2bf(v.w);
  }
  __syncthreads();
  for (int rr = r; rr < 64; rr += 16) {
    ushort4 o;
    o.x = tile[c4 + 0][rr]; o.y = tile[c4 + 1][rr];
    o.z = tile[c4 + 2][rr]; o.w = tile[c4 + 3][rr];
    *(ushort4*)(Wt + (size_t)(n0 + rr) * DMODEL + k0 + c4) = o;
  }
}

// ---------------- LayerNorm -> h_bf16, and x -> x_bf16 ----------------
__global__ __launch_bounds__(256) void ln_kernel(
    const float* __restrict__ x, const float* __restrict__ gamma,
    const float* __restrict__ beta,
    unsigned short* __restrict__ hb, unsigned short* __restrict__ xb) {
  int l = blockIdx.x, t = threadIdx.x;
  float4 v = ((const float4*)(x + (size_t)l * DMODEL))[t];
  float s  = v.x + v.y + v.z + v.w;
  float s2 = v.x * v.x + v.y * v.y + v.z * v.z + v.w * v.w;
  for (int off = 32; off; off >>= 1) {
    s  += __shfl_down(s, off);
    s2 += __shfl_down(s2, off);
  }
  __shared__ float rs[4], rs2[4];
  int wave = t >> 6, lane = t & 63;
  if (lane == 0) { rs[wave] = s; rs2[wave] = s2; }
  __syncthreads();
  float mean = (rs[0] + rs[1] + rs[2] + rs[3]) * (1.0f / DMODEL);
  float var  = (rs2[0] + rs2[1] + rs2[2] + rs2[3]) * (1.0f / DMODEL) - mean * mean;
  float rstd = rsqrtf(var + 1e-5f);
  float4 g = ((const float4*)gamma)[t];
  float4 b = ((const float4*)beta)[t];
  ushort4 hh, xx;
  hh.x = f2bf((v.x - mean) * rstd * g.x + b.x);
  hh.y = f2bf((v.y - mean) * rstd * g.y + b.y);
  hh.z = f2bf((v.z - mean) * rstd * g.z + b.z);
  hh.w = f2bf((v.w - mean) * rstd * g.w + b.w);
  xx.x = f2bf(v.x); xx.y = f2bf(v.y); xx.z = f2bf(v.z); xx.w = f2bf(v.w);
  ((ushort4*)(hb + (size_t)l * DMODEL))[t] = hh;
  ((ushort4*)(xb + (size_t)l * DMODEL))[t] = xx;
}

// ---------------- direct-fragment MFMA GEMM core: 64x64 tile, wave = 16 rows ----------------
__device__ __forceinline__ void mfma_gemm_64x64(
    const unsigned short* __restrict__ A, const unsigned short* __restrict__ Bt,
    int row0, int ncol0, int lm, int quad, f32x4 acc[4]) {
  for (int k0 = 0; k0 < DMODEL; k0 += 64) {
    short8 a0 = *(const short8*)(A + (size_t)(row0 + lm) * DMODEL + k0 + quad * 8);
    short8 a1 = *(const short8*)(A + (size_t)(row0 + lm) * DMODEL + k0 + 32 + quad * 8);
#pragma unroll
    for (int c = 0; c < 4; c++) {
      const unsigned short* bp = Bt + (size_t)(ncol0 + c * 16 + lm) * DMODEL + k0 + quad * 8;
      short8 b0 = *(const short8*)(bp);
      short8 b1 = *(const short8*)(bp + 32);
      acc[c] = __builtin_amdgcn_mfma_f32_16x16x32_bf16(a0, b0, acc[c], 0, 0, 0);
      acc[c] = __builtin_amdgcn_mfma_f32_16x16x32_bf16(a1, b1, acc[c], 0, 0, 0);
    }
  }
}

// ---------------- QKV GEMM + RoPE epilogue ----------------
__global__ __launch_bounds__(256) void gemm_qkv(
    const unsigned short* __restrict__ hb,
    const unsigned short* __restrict__ Wqt, const unsigned short* __restrict__ Wkt,
    const unsigned short* __restrict__ Wvt,
    unsigned short* __restrict__ qb, unsigned short* __restrict__ kb,
    unsigned short* __restrict__ vT) {
  int which = blockIdx.z;
  const unsigned short* Bt = (which == 0) ? Wqt : (which == 1) ? Wkt : Wvt;
  int wave = threadIdx.x >> 6, lane = threadIdx.x & 63;
  int lm = lane & 15, quad = lane >> 4;
  int it = blockIdx.x, head = blockIdx.y;
  int row0 = it * 64 + wave * 16;
  f32x4 acc[4] = {};
  mfma_gemm_64x64(hb, Bt, row0, head * 64, lm, quad, acc);
  __shared__ float tile[64][65];
#pragma unroll
  for (int c = 0; c < 4; c++)
#pragma unroll
    for (int r2 = 0; r2 < 4; r2++)
      tile[wave * 16 + quad * 4 + r2][c * 16 + lm] = acc[c][r2];
  __syncthreads();
  int r = threadIdx.x >> 2, seg = threadIdx.x & 3;
  int lrow = it * 64 + r;
  float vals[16];
#pragma unroll
  for (int i2 = 0; i2 < 16; i2++) vals[i2] = tile[r][seg * 16 + i2];
  if (seg == 0) {  // RoPE on dh 0..15 (applies to q, k AND v per reference)
    float outv[16];
#pragma unroll
    for (int j = 0; j < 8; j++) {
      float invf = powf(10000.f, -(float)j * 0.125f);
      float f = (float)lrow * invf;
      float cs = cosf(f), sn = sinf(f);
      outv[j]     = vals[j] * cs - vals[j + 8] * sn;
      outv[j + 8] = vals[j + 8] * cs + vals[j] * sn;
    }
#pragma unroll
    for (int j = 0; j < 16; j++) vals[j] = outv[j];
  }
  if (which < 2) {
    unsigned short* dst = ((which == 0) ? qb : kb) + ((size_t)head * LLEN + lrow) * DHEAD + seg * 16;
    union { unsigned short u[16]; uint4 v[2]; } tmp;
#pragma unroll
    for (int i2 = 0; i2 < 16; i2++) tmp.u[i2] = f2bf(vals[i2]);
    *(uint4*)dst = tmp.v[0];
    *((uint4*)dst + 1) = tmp.v[1];
  } else {
    __syncthreads();
#pragma unroll
    for (int i2 = 0; i2 < 16; i2++) tile[r][seg * 16 + i2] = vals[i2];
    __syncthreads();
    int dh = threadIdx.x >> 2, ls = threadIdx.x & 3;
    union { unsigned short u[16]; uint4 v[2]; } tmp;
#pragma unroll
    for (int i2 = 0; i2 < 16; i2++) tmp.u[i2] = f2bf(tile[ls * 16 + i2][dh]);
    unsigned short* dst = vT + ((size_t)head * DHEAD + dh) * LLEN + it * 64 + ls * 16;
    *(uint4*)dst = tmp.v[0];
    *((uint4*)dst + 1) = tmp.v[1];
  }
}

// ---------------- fused attention: j-split across 4 waves + LDS reduce ----------------
// One block (4 waves) per 16-row group g. Wave wv handles tiles jt = wv, wv+4, ...
// No-max softmax is linear, so per-wave partial (lsum, oacc) just add.
// 1-D grid 2048: h = bid&15, g = bid>>4 -> a CU's resident blocks span the g
// range (ids differ by 256 -> g differs by 16), so per-CU work is balanced.
__global__ __launch_bounds__(256, 4) void attn_kernel(
    const unsigned short* __restrict__ qb, const unsigned short* __restrict__ kb,
    const unsigned short* __restrict__ vT, const float* __restrict__ prev,
    float* __restrict__ dots, unsigned short* __restrict__ ob,
    float* __restrict__ rinvg) {
  int bid = blockIdx.x;
  int h = bid & 15, g = bid >> 4;       // g in 0..127
  int wv = threadIdx.x >> 6, lane = threadIdx.x & 63;
  int lm = lane & 15, quad = lane >> 4;
  int row0 = g * 16;
  int jt_end = g >> 2;                  // inclusive diagonal tile
  const unsigned short* q = qb + (size_t)h * LLEN * DHEAD;
  const unsigned short* k = kb + (size_t)h * LLEN * DHEAD;
  const unsigned short* v = vT + (size_t)h * DHEAD * LLEN;
  const float* pr = prev + (size_t)h * LLEN * LLEN;
  float* drow = dots + (size_t)h * LLEN * LLEN;
  float slope = exp2f(-8.0f * (float)(h + 1) / (float)NHEAD);

  // LDS union: pt (9216 B, used in loop) overlaps red/redl (16640 B, used after
  // the first barrier, when all waves are done with pt).
  __shared__ __align__(16) char smem[16640];
  unsigned short (*pt)[16][72] = (unsigned short (*)[16][72])smem;
  float (*red)[64][16] = (float (*)[64][16])smem;
  float* redl = (float*)(smem + 16384);   // [4][16]

  short8 qa0 = *(const short8*)(q + (size_t)(row0 + lm) * DHEAD + quad * 8);
  short8 qa1 = *(const short8*)(q + (size_t)(row0 + lm) * DHEAD + 32 + quad * 8);
  f32x4 oacc[4] = {};
  float lsum[4] = {0.f, 0.f, 0.f, 0.f};

  for (int jt = wv; jt <= jt_end; jt += 4) {
    // ---- QK^T ----
    f32x4 s[4];
#pragma unroll
    for (int c = 0; c < 4; c++) {
      const unsigned short* kp = k + (size_t)(jt * 64 + c * 16 + lm) * DHEAD + quad * 8;
      short8 b0 = *(const short8*)kp;
      short8 b1 = *(const short8*)(kp + 32);
      f32x4 z = {};
      z = __builtin_amdgcn_mfma_f32_16x16x32_bf16(qa0, b0, z, 0, 0, 0);
      z = __builtin_amdgcn_mfma_f32_16x16x32_bf16(qa1, b1, z, 0, 0, 0);
      s[c] = z;
    }
    // ---- dots write + unnormalized exp + lsum + P tile to LDS (wave-private) ----
#pragma unroll
    for (int c = 0; c < 4; c++) {
      int j = jt * 64 + c * 16 + lm;
#pragma unroll
      for (int r = 0; r < 4; r++) {
        int i = row0 + quad * 4 + r;
        int rel = i - j;
        float bias = (rel >= 0) ? (-slope * (float)rel) : NEGF;
        float d = fmaf(s[c][r], SCALE, pr[(size_t)i * LLEN + j]) + bias;
        drow[(size_t)i * LLEN + j] = d;
        float p = __expf(d);   // no-max softmax: d bounded ~±30, safe in f32
        lsum[r] += p;
        pt[wv][quad * 4 + r][c * 16 + lm] = f2bf(p);
      }
    }
    // ---- PV accumulate with unnormalized p ----
    short8 pa0 = *(const short8*)&pt[wv][lm][quad * 8];
    short8 pa1 = *(const short8*)&pt[wv][lm][32 + quad * 8];
#pragma unroll
    for (int c = 0; c < 4; c++) {
      const unsigned short* vp = v + (size_t)(c * 16 + lm) * LLEN + jt * 64 + quad * 8;
      short8 b0 = *(const short8*)vp;
      short8 b1 = *(const short8*)(vp + 32);
      oacc[c] = __builtin_amdgcn_mfma_f32_16x16x32_bf16(pa0, b0, oacc[c], 0, 0, 0);
      oacc[c] = __builtin_amdgcn_mfma_f32_16x16x32_bf16(pa1, b1, oacc[c], 0, 0, 0);
    }
  }
  // ---- intra-wave lsum reduce over the 16 lanes of each quad ----
#pragma unroll
  for (int r = 0; r < 4; r++) {
#pragma unroll
    for (int off = 1; off < 16; off <<= 1) lsum[r] += __shfl_xor(lsum[r], off, 16);
  }
  __syncthreads();   // all waves done with pt -> safe to overlay red
  // ---- store per-wave partials ----
#pragma unroll
  for (int c = 0; c < 4; c++)
#pragma unroll
    for (int r = 0; r < 4; r++)
      red[wv][lane][c * 4 + r] = oacc[c][r];
  if (lm == 0) {
#pragma unroll
    for (int r = 0; r < 4; r++) redl[wv * 16 + quad * 4 + r] = lsum[r];
  }
  __syncthreads();
  // ---- cross-wave combine + O write ----
  {
    int t = threadIdx.x;
    int ln = t & 63, idx0 = t >> 6;
    int qd = ln >> 4, lmm = ln & 15;
#pragma unroll
    for (int kk = 0; kk < 4; kk++) {
      int idx = idx0 * 4 + kk;      // idx = c*4 + r
      int c = idx >> 2, r = idx & 3;
      float sv = red[0][ln][idx] + red[1][ln][idx] + red[2][ln][idx] + red[3][ln][idx];
      int rr = qd * 4 + r;
      float rs = redl[rr] + redl[16 + rr] + redl[32 + rr] + redl[48 + rr];
      ob[(size_t)(row0 + rr) * DMODEL + h * DHEAD + c * 16 + lmm] = f2bf(sv / rs);
    }
    if (t < 16) {
      float rs = redl[t] + redl[16 + t] + redl[32 + t] + redl[48 + t];
      rinvg[(size_t)h * LLEN + row0 + t] = 1.0f / rs;
    }
  }
  // ---- masked dots filler (256 threads) ----
  int jstart = (jt_end + 1) * 64;
  int ncols4 = (LLEN - jstart) >> 2;
  if (ncols4 > 0) {
    float4 negv = {NEGF, NEGF, NEGF, NEGF};
    int r = threadIdx.x >> 4, t16 = threadIdx.x & 15;  // r in 0..15
    size_t base = (size_t)(row0 + r) * LLEN + jstart;
    for (int c4 = t16; c4 < ncols4; c4 += 16)
      *(float4*)(drow + base + c4 * 4) = negv;
  }
}

// ---------------- attn_map normalization: attn = exp(dots) * rinv (streamed) ----
__global__ __launch_bounds__(256) void attn_norm(
    const float* __restrict__ dots, const float* __restrict__ rinvg,
    float* __restrict__ attn) {
  int h = blockIdx.y;
  int i0 = blockIdx.x * 8;
  const float* dr = dots + (size_t)h * LLEN * LLEN;
  float* ar = attn + (size_t)h * LLEN * LLEN;
#pragma unroll
  for (int rr = 0; rr < 8; rr++) {
    int i = i0 + rr;
    float rinv = rinvg[(size_t)h * LLEN + i];
    int nwr4 = ((i >> 6) + 1) * 16;  // float4s in the written (non-filler) region
#pragma unroll
    for (int jc = 0; jc < 2; jc++) {
      int j4 = threadIdx.x + jc * 256;
      size_t idx = (size_t)i * LLEN + (size_t)j4 * 4;
      if (j4 < nwr4) {
        float4 d = *(const float4*)(dr + idx);
        float4 o;
        o.x = __expf(d.x) * rinv;  // exp(NEGF) == 0 handles in-tile masked cols
        o.y = __expf(d.y) * rinv;
        o.z = __expf(d.z) * rinv;
        o.w = __expf(d.w) * rinv;
        *(float4*)(ar + idx) = o;
      } else {
        float4 z = {0.f, 0.f, 0.f, 0.f};
        *(float4*)(ar + idx) = z;
      }
    }
  }
}

// ---------------- fused gate+output GEMM: y = sigmoid(x@Wg+bg) * (o@Wo+bo) + x ----
// Two interleaved K-loops double per-wave ILP (the pair was latency-bound at
// 2 waves/SIMD), and the gate round-trip (16 MB) + one launch are eliminated.
__global__ __launch_bounds__(256) void gemm_gateout(
    const unsigned short* __restrict__ xb, const unsigned short* __restrict__ Wgt,
    const float* __restrict__ bg,
    const unsigned short* __restrict__ ob, const unsigned short* __restrict__ Wot,
    const float* __restrict__ bo,
    const float* __restrict__ x, float* __restrict__ y) {
  int wave = threadIdx.x >> 6, lane = threadIdx.x & 63;
  int lm = lane & 15, quad = lane >> 4;
  int row0 = blockIdx.x * 64 + wave * 16, ncol0 = blockIdx.y * 64;
  f32x4 accg[4] = {}, acco[4] = {};
  for (int k0 = 0; k0 < DMODEL; k0 += 64) {
    short8 ax0 = *(const short8*)(xb + (size_t)(row0 + lm) * DMODEL + k0 + quad * 8);
    short8 ax1 = *(const short8*)(xb + (size_t)(row0 + lm) * DMODEL + k0 + 32 + quad * 8);
    short8 ao0 = *(const short8*)(ob + (size_t)(row0 + lm) * DMODEL + k0 + quad * 8);
    short8 ao1 = *(const short8*)(ob + (size_t)(row0 + lm) * DMODEL + k0 + 32 + quad * 8);
#pragma unroll
    for (int c = 0; c < 4; c++) {
      const unsigned short* bgp = Wgt + (size_t)(ncol0 + c * 16 + lm) * DMODEL + k0 + quad * 8;
      const unsigned short* bop = Wot + (size_t)(ncol0 + c * 16 + lm) * DMODEL + k0 + quad * 8;
      short8 g0 = *(const short8*)(bgp);
      short8 g1 = *(const short8*)(bgp + 32);
      short8 o0 = *(const short8*)(bop);
      short8 o1 = *(const short8*)(bop + 32);
      accg[c] = __builtin_amdgcn_mfma_f32_16x16x32_bf16(ax0, g0, accg[c], 0, 0, 0);
      acco[c] = __builtin_amdgcn_mfma_f32_16x16x32_bf16(ao0, o0, acco[c], 0, 0, 0);
      accg[c] = __builtin_amdgcn_mfma_f32_16x16x32_bf16(ax1, g1, accg[c], 0, 0, 0);
      acco[c] = __builtin_amdgcn_mfma_f32_16x16x32_bf16(ao1, o1, acco[c], 0, 0, 0);
    }
  }
#pragma unroll
  for (int c = 0; c < 4; c++) {
    int col = ncol0 + c * 16 + lm;
    float bgv = bg[col], bov = bo[col];
#pragma unroll
    for (int r = 0; r < 4; r++) {
      int i = row0 + quad * 4 + r;
      size_t idx = (size_t)i * DMODEL + col;
      float gt = 1.0f / (1.0f + __expf(-(accg[c][r] + bgv)));
      y[idx] = gt * (acco[c][r] + bov) + x[idx];
    }
  }
}

extern "C" void kernel_launch(void* const* d_in, const int* in_sizes, int n_in,
                              void* d_out, int out_size, void* d_ws, size_t ws_size,
                              hipStream_t stream) {
  const float* x     = (const float*)d_in[0];
  const float* prev  = (const float*)d_in[1];
  const float* Wq    = (const float*)d_in[2];
  const float* Wk    = (const float*)d_in[3];
  const float* Wv    = (const float*)d_in[4];
  const float* Wo    = (const float*)d_in[5];
  const float* bo    = (const float*)d_in[6];
  const float* gamma = (const float*)d_in[7];
  const float* beta  = (const float*)d_in[8];
  const float* Wg    = (const float*)d_in[9];
  const float* bg    = (const float*)d_in[10];

  float* y    = (float*)d_out;
  float* attn = y + 2097152;          // 2048*1024
  float* dots = attn + 67108864;      // 16*2048*2048

  char* ws = (char*)d_ws;
  unsigned short* hb  = (unsigned short*)(ws + 0);
  unsigned short* xb  = (unsigned short*)(ws + 4194304);
  unsigned short* Wqt = (unsigned short*)(ws + 8388608);
  unsigned short* Wkt = (unsigned short*)(ws + 10485760);
  unsigned short* Wvt = (unsigned short*)(ws + 12582912);
  unsigned short* Wot = (unsigned short*)(ws + 14680064);
  unsigned short* Wgt = (unsigned short*)(ws + 16777216);
  unsigned short* qb  = (unsigned short*)(ws + 18874368);
  unsigned short* kb  = (unsigned short*)(ws + 23068672);
  unsigned short* vT  = (unsigned short*)(ws + 27262976);
  unsigned short* ob  = (unsigned short*)(ws + 31457280);
  // rinv per (head,row): reuses the hb region, which is dead after gemm_qkv.
  float*          rinvg = (float*)(ws + 0);

  transpose_w<<<dim3(16, 16, 5), 256, 0, stream>>>(Wq, Wk, Wv, Wo, Wg, Wqt, Wkt, Wvt, Wot, Wgt);
  ln_kernel<<<dim3(2048), 256, 0, stream>>>(x, gamma, beta, hb, xb);
  gemm_qkv<<<dim3(32, 16, 3), 256, 0, stream>>>(hb, Wqt, Wkt, Wvt, qb, kb, vT);
  attn_kernel<<<dim3(2048), 256, 0, stream>>>(qb, kb, vT, prev, dots, ob, rinvg);
  attn_norm<<<dim3(256, 16), 256, 0, stream>>>(dots, rinvg, attn);
  gemm_gateout<<<dim3(32, 16), 256, 0, stream>>>(xb, Wgt, bg, ob, Wot, bo, x, y);
}